// Round 2
// baseline (433.144 us; speedup 1.0000x reference)
//
#include <hip/hip_runtime.h>

// SelfAttentionFusion: 3D window attention, WS=4, N=64 tokens/window, C=128, 4 heads x 32.
// 4096 windows, one 256-thread block each. Inputs/outputs fp32; bf16 internally for MFMA.

typedef __attribute__((ext_vector_type(8))) short bf16x8;
typedef __attribute__((ext_vector_type(4))) float f32x4;

__device__ __forceinline__ unsigned short f2b(float f) {
    union { float f; unsigned int i; } v; v.f = f;
    unsigned int i = v.i;
    return (unsigned short)((i + 0x7FFFu + ((i >> 16) & 1u)) >> 16);
}

// pack 8 consecutive fp32 (32B, 16B-aligned) -> bf16x8 fragment
__device__ __forceinline__ bf16x8 load_w8(const float* __restrict__ p) {
    float4 a = *reinterpret_cast<const float4*>(p);
    float4 b = *reinterpret_cast<const float4*>(p + 4);
    bf16x8 r;
    r[0] = (short)f2b(a.x); r[1] = (short)f2b(a.y); r[2] = (short)f2b(a.z); r[3] = (short)f2b(a.w);
    r[4] = (short)f2b(b.x); r[5] = (short)f2b(b.y); r[6] = (short)f2b(b.z); r[7] = (short)f2b(b.w);
    return r;
}

// ---- LDS layout (units: ushort elements). Total 32768 = 64 KB. ----
// XIN [0,8192)      xin[t][128]   live: s1 write .. s2 read
// X   [8192,16384)  x[t][128]     live: s2 write .. s3 read
// Q   [0,8192)      q[h][t][32]   live: s3 write .. s4 frag preload   (alias XIN)
// K   [16384,24576) k[h][t][32]   live: s3 write .. s4 frag preload
// V   [24576,32768) v[h][d][64]   live: s3 write .. s4 PV frag preload
// P   [0,16384)     p[h][n][64]   live: s4 post-barrier .. s4 PV      (alias Q+X)
// AO  [16384,24576) ao[t][128]    live: s4 PV write .. s5 read        (alias K)
// FU  [24576,32768) fu[c][64] f32 live: s5 write .. s6 read           (alias V)
#define XIN_OFF 0
#define X_OFF   8192
#define Q_OFF   0
#define K_OFF   16384
#define V_OFF   24576
#define P_OFF   0
#define AO_OFF  16384
#define FU_OFF  24576

// 128-wide rows (16 chunks of 8): xor-swizzle chunk so fragment ds_read_b128s stay <=2-way
__device__ __forceinline__ int idx128(int base, int t, int c) {
    int swz = ((c >> 3) ^ (t & 15) ^ ((t >> 4) & 3)) & 15;
    return base + t * 128 + (swz << 3) + (c & 7);
}
// 32-wide rows (4 chunks)
__device__ __forceinline__ int idxqk(int base, int h, int t, int d) {
    int swz = ((d >> 3) ^ (t & 3) ^ ((t >> 2) & 3)) & 3;
    return base + h * 2048 + t * 32 + (swz << 3) + (d & 7);
}
// 64-wide rows (8 chunks)
__device__ __forceinline__ int idxv(int h, int d, int m) {
    int swz = ((m >> 3) ^ (d & 7)) & 7;
    return V_OFF + h * 2048 + d * 64 + (swz << 3) + (m & 7);
}
__device__ __forceinline__ int idxp(int h, int n, int m) {
    int swz = ((m >> 3) ^ (n & 7)) & 7;
    return P_OFF + h * 4096 + n * 64 + (swz << 3) + (m & 7);
}
// FU: float units, 64 rows x 64, chunk-of-4 swizzle
__device__ __forceinline__ int idxfu(int c, int t) {
    int swz = ((t >> 2) ^ (c & 15)) & 15;
    return c * 64 + (swz << 2) + (t & 3);
}

__global__ __launch_bounds__(256, 2) void win_attn_kernel(
    const float* __restrict__ cfeat,
    const float* __restrict__ tfeat,
    const float* __restrict__ conv_w,
    const float* __restrict__ conv_b,
    const float* __restrict__ trans_w,
    const float* __restrict__ trans_b,
    const float* __restrict__ qkv_w,
    const float* __restrict__ qkv_b,
    const float* __restrict__ proj_w,
    const float* __restrict__ proj_b,
    const float* __restrict__ btab,
    const int* __restrict__ ridx,
    float* __restrict__ out)
{
    __shared__ unsigned short smem[32768];  // 64 KB
    float* fuf = reinterpret_cast<float*>(&smem[FU_OFF]);

    const int tid  = threadIdx.x;
    const int lane = tid & 63;
    const int wv   = tid >> 6;       // wave 0..3
    const int col  = lane & 15;      // MFMA n / A-m index
    const int quad = lane >> 4;      // MFMA k-chunk / row-quad

    // XCD swizzle: consecutive same-XCD dispatch slots get consecutive wx -> L2 line sharing
    int b   = blockIdx.x;
    int wid = ((b & 7) << 9) | (b >> 3);
    int wz = wid >> 8, wy = (wid >> 4) & 15, wx = wid & 15;
    const int vbase = wz * 16384 + wy * 256 + wx * 4;   // element offset of window origin

    // ---- stage 1: global fp32 -> bf16 LDS xin[t][cc] (cc: 0..63 conv, 64..127 trans) ----
#pragma unroll
    for (int it = 0; it < 8; ++it) {
        int id  = tid + (it << 8);          // 0..2047
        int inp = id >> 10;
        int rem = id & 1023;
        int c   = rem >> 4;
        int z   = (rem >> 2) & 3, y = rem & 3;
        const float* src = inp ? tfeat : cfeat;
        float4 v = *reinterpret_cast<const float4*>(src + c * 262144 + vbase + z * 4096 + y * 64);
        int cc = inp * 64 + c;
        int tb = z * 16 + y * 4;
        smem[idx128(XIN_OFF, tb + 0, cc)] = f2b(v.x);
        smem[idx128(XIN_OFF, tb + 1, cc)] = f2b(v.y);
        smem[idx128(XIN_OFF, tb + 2, cc)] = f2b(v.z);
        smem[idx128(XIN_OFF, tb + 3, cc)] = f2b(v.w);
    }
    __syncthreads();

    // ---- stage 2: input projection -> x[t][o], o<64 conv, o>=64 trans ----
    {
        int half = wv >> 1;
        const float* wmat = half ? trans_w : conv_w;
        const float* bvec = half ? trans_b : conv_b;
        bf16x8 afr[4][2];
#pragma unroll
        for (int tt = 0; tt < 4; ++tt)
#pragma unroll
            for (int kt = 0; kt < 2; ++kt)
                afr[tt][kt] = *reinterpret_cast<const bf16x8*>(
                    &smem[idx128(XIN_OFF, tt * 16 + col, half * 64 + kt * 32 + quad * 8)]);
#pragma unroll
        for (int otl = 0; otl < 2; ++otl) {
            int rt  = (wv & 1) * 2 + otl;   // weight row-tile 0..3
            int row = rt * 16 + col;        // out channel within half
            bf16x8 bfr[2];
#pragma unroll
            for (int kt = 0; kt < 2; ++kt)
                bfr[kt] = load_w8(wmat + row * 64 + kt * 32 + quad * 8);
            float bias = bvec[row];
            int oc = half * 64 + row;
#pragma unroll
            for (int tt = 0; tt < 4; ++tt) {
                f32x4 acc = {0.f, 0.f, 0.f, 0.f};
#pragma unroll
                for (int kt = 0; kt < 2; ++kt)
                    acc = __builtin_amdgcn_mfma_f32_16x16x32_bf16(afr[tt][kt], bfr[kt], acc, 0, 0, 0);
#pragma unroll
                for (int g = 0; g < 4; ++g)
                    smem[idx128(X_OFF, tt * 16 + quad * 4 + g, oc)] = f2b(acc[g] + bias);
            }
        }
    }
    __syncthreads();

    // ---- stage 3: QKV = x @ qkv_w^T + qkv_b; q pre-scaled; q/k [h][t][32], v [h][d][64] ----
    {
        bf16x8 afr[4][4];
#pragma unroll
        for (int tt = 0; tt < 4; ++tt)
#pragma unroll
            for (int kt = 0; kt < 4; ++kt)
                afr[tt][kt] = *reinterpret_cast<const bf16x8*>(
                    &smem[idx128(X_OFF, tt * 16 + col, kt * 32 + quad * 8)]);
        for (int rt = wv * 6; rt < wv * 6 + 6; ++rt) {
            int r = rt * 16 + col;          // qkv output row 0..383
            bf16x8 bfr[4];
#pragma unroll
            for (int kt = 0; kt < 4; ++kt)
                bfr[kt] = load_w8(qkv_w + r * 128 + kt * 32 + quad * 8);
            float bias = qkv_b[r];
            int sel = r >> 7;           // 0:q 1:k 2:v (uniform per rt)
            int h   = (r >> 5) & 3;     // uniform per rt
            int d0  = r & 31;
#pragma unroll
            for (int tt = 0; tt < 4; ++tt) {
                f32x4 acc = {0.f, 0.f, 0.f, 0.f};
#pragma unroll
                for (int kt = 0; kt < 4; ++kt)
                    acc = __builtin_amdgcn_mfma_f32_16x16x32_bf16(afr[tt][kt], bfr[kt], acc, 0, 0, 0);
#pragma unroll
                for (int g = 0; g < 4; ++g) {
                    int t = tt * 16 + quad * 4 + g;
                    float v = acc[g] + bias;
                    if (sel == 0)      smem[idxqk(Q_OFF, h, t, d0)] = f2b(v * 0.17677669529663689f);
                    else if (sel == 1) smem[idxqk(K_OFF, h, t, d0)] = f2b(v);
                    else               smem[idxv(h, d0, t)] = f2b(v);
                }
            }
        }
    }
    __syncthreads();

    // ---- stage 4: per-head attention (wave wv <-> head wv) ----
    {
        const int h = wv;
        bf16x8 qfr[4], kfr[4];
#pragma unroll
        for (int nt = 0; nt < 4; ++nt) {
            qfr[nt] = *reinterpret_cast<const bf16x8*>(&smem[idxqk(Q_OFF, h, nt * 16 + col, quad * 8)]);
            kfr[nt] = *reinterpret_cast<const bf16x8*>(&smem[idxqk(K_OFF, h, nt * 16 + col, quad * 8)]);
        }
        __syncthreads();  // all Q/K reads done; P (over Q/X) and AO (over K) writes may begin

#pragma unroll
        for (int nt = 0; nt < 4; ++nt) {
            f32x4 s[4];
            const f32x4 zero = {0.f, 0.f, 0.f, 0.f};
#pragma unroll
            for (int mt = 0; mt < 4; ++mt)
                s[mt] = __builtin_amdgcn_mfma_f32_16x16x32_bf16(qfr[nt], kfr[mt], zero, 0, 0, 0);
            // + relative position bias (fp32 gather)
#pragma unroll
            for (int mt = 0; mt < 4; ++mt) {
                int m = mt * 16 + col;
#pragma unroll
                for (int g = 0; g < 4; ++g) {
                    int n = nt * 16 + quad * 4 + g;
                    s[mt][g] += btab[ridx[n * 64 + m] * 4 + h];
                }
            }
            // softmax over m: row n lives in the 16 lanes of one quad x 4 regs
#pragma unroll
            for (int g = 0; g < 4; ++g) {
                float mx = fmaxf(fmaxf(s[0][g], s[1][g]), fmaxf(s[2][g], s[3][g]));
#pragma unroll
                for (int o = 1; o < 16; o <<= 1) mx = fmaxf(mx, __shfl_xor(mx, o, 64));
                float e0 = __expf(s[0][g] - mx), e1 = __expf(s[1][g] - mx);
                float e2 = __expf(s[2][g] - mx), e3 = __expf(s[3][g] - mx);
                float sm = e0 + e1 + e2 + e3;
#pragma unroll
                for (int o = 1; o < 16; o <<= 1) sm += __shfl_xor(sm, o, 64);
                float inv = 1.0f / sm;
                s[0][g] = e0 * inv; s[1][g] = e1 * inv; s[2][g] = e2 * inv; s[3][g] = e3 * inv;
            }
#pragma unroll
            for (int mt = 0; mt < 4; ++mt) {
                int m = mt * 16 + col;
#pragma unroll
                for (int g = 0; g < 4; ++g)
                    smem[idxp(h, nt * 16 + quad * 4 + g, m)] = f2b(s[mt][g]);
            }
        }

        // PV: O[n][d] = sum_m P[n][m] V[m][d]  (V stored transposed v[d][m])
        bf16x8 pfr[4][2], vfr[2][2];
#pragma unroll
        for (int dt = 0; dt < 2; ++dt)
#pragma unroll
            for (int kt = 0; kt < 2; ++kt)
                vfr[dt][kt] = *reinterpret_cast<const bf16x8*>(
                    &smem[idxv(h, dt * 16 + col, kt * 32 + quad * 8)]);
#pragma unroll
        for (int nt = 0; nt < 4; ++nt)
#pragma unroll
            for (int kt = 0; kt < 2; ++kt)
                pfr[nt][kt] = *reinterpret_cast<const bf16x8*>(
                    &smem[idxp(h, nt * 16 + col, kt * 32 + quad * 8)]);
#pragma unroll
        for (int nt = 0; nt < 4; ++nt)
#pragma unroll
            for (int dt = 0; dt < 2; ++dt) {
                f32x4 acc = {0.f, 0.f, 0.f, 0.f};
#pragma unroll
                for (int kt = 0; kt < 2; ++kt)
                    acc = __builtin_amdgcn_mfma_f32_16x16x32_bf16(pfr[nt][kt], vfr[dt][kt], acc, 0, 0, 0);
#pragma unroll
                for (int g = 0; g < 4; ++g)
                    smem[idx128(AO_OFF, nt * 16 + quad * 4 + g, h * 32 + dt * 16 + col)] = f2b(acc[g]);
            }
    }
    __syncthreads();

    // ---- stage 5: proj + fold halves + bias + residual -> fu[c][t] (fp32) ----
    {
        bf16x8 afr[4][4];
#pragma unroll
        for (int tt = 0; tt < 4; ++tt)
#pragma unroll
            for (int kt = 0; kt < 4; ++kt)
                afr[tt][kt] = *reinterpret_cast<const bf16x8*>(
                    &smem[idx128(AO_OFF, tt * 16 + col, kt * 32 + quad * 8)]);
        int o1 = wv * 16 + col;         // 0..63
        int o2 = 64 + o1;
        bf16x8 b1[4], b2[4];
#pragma unroll
        for (int kt = 0; kt < 4; ++kt) {
            b1[kt] = load_w8(proj_w + o1 * 128 + kt * 32 + quad * 8);
            b2[kt] = load_w8(proj_w + o2 * 128 + kt * 32 + quad * 8);
        }
        float pb = proj_b[o1] + proj_b[o2];
#pragma unroll
        for (int tt = 0; tt < 4; ++tt) {
            f32x4 a1 = {0.f, 0.f, 0.f, 0.f}, a2 = {0.f, 0.f, 0.f, 0.f};
#pragma unroll
            for (int kt = 0; kt < 4; ++kt) {
                a1 = __builtin_amdgcn_mfma_f32_16x16x32_bf16(afr[tt][kt], b1[kt], a1, 0, 0, 0);
                a2 = __builtin_amdgcn_mfma_f32_16x16x32_bf16(afr[tt][kt], b2[kt], a2, 0, 0, 0);
            }
#pragma unroll
            for (int g = 0; g < 4; ++g) {
                int t = tt * 16 + quad * 4 + g;
                int voff = vbase + ((t >> 4) << 12) + (((t >> 2) & 3) << 6) + (t & 3);
                float resid = cfeat[o1 * 262144 + voff];   // L2-hot re-read
                fuf[idxfu(o1, t)] = a1[g] + a2[g] + pb + resid;
            }
        }
    }
    __syncthreads();

    // ---- stage 6: coalesced store (16 B float4 per thread per iter) ----
#pragma unroll
    for (int it = 0; it < 4; ++it) {
        int id = tid + (it << 8);       // 0..1023
        int c  = id >> 4;
        int z  = (id >> 2) & 3, y = id & 3;
        int t  = z * 16 + y * 4;
        float4 val = *reinterpret_cast<const float4*>(&fuf[idxfu(c, t)]);
        *reinterpret_cast<float4*>(out + c * 262144 + vbase + z * 4096 + y * 64) = val;
    }
}

extern "C" void kernel_launch(void* const* d_in, const int* in_sizes, int n_in,
                              void* d_out, int out_size, void* d_ws, size_t ws_size,
                              hipStream_t stream) {
    (void)in_sizes; (void)n_in; (void)out_size; (void)d_ws; (void)ws_size;
    win_attn_kernel<<<dim3(4096), dim3(256), 0, stream>>>(
        (const float*)d_in[0],  // conv_feat
        (const float*)d_in[1],  // transformer_feat
        (const float*)d_in[2],  // conv_w
        (const float*)d_in[3],  // conv_b
        (const float*)d_in[4],  // trans_w
        (const float*)d_in[5],  // trans_b
        (const float*)d_in[6],  // qkv_w
        (const float*)d_in[7],  // qkv_b
        (const float*)d_in[8],  // proj_w
        (const float*)d_in[9],  // proj_b
        (const float*)d_in[10], // rel_bias_table
        (const int*)d_in[11],   // rel_index
        (float*)d_out);
}

// Round 3
// 318.488 us; speedup vs baseline: 1.3600x; 1.3600x over previous
//
#include <hip/hip_runtime.h>

// SelfAttentionFusion: 3D window attention, WS=4, N=64 tokens/window, C=128, 4 heads x 32.
// 4096 windows, one 256-thread block each. fp32 I/O; bf16 internally for MFMA.
// Prep kernel pre-converts weights to fragment-ordered bf16 and pre-expands the
// relative-position bias into MFMA C-layout float4 fragments (both in d_ws).

typedef __attribute__((ext_vector_type(8))) short bf16x8;
typedef __attribute__((ext_vector_type(4))) float f32x4;

__device__ __forceinline__ unsigned short f2b(float f) {
    union { float f; unsigned int i; } v; v.f = f;
    unsigned int i = v.i;
    return (unsigned short)((i + 0x7FFFu + ((i >> 16) & 1u)) >> 16);
}

// ---- workspace layout ----
// wsW (ushort): fragment-ordered bf16 weights, group = 64 lanes x 8 elems per tile
//   conv tiles  [0,   512) groups   (8 tiles:  rt*2+kt, rt<4, kt<2)
//   trans tiles [512, 1024)
//   qkv tiles   [1024,7168)         (96 tiles: rt*4+kt, rt<24, kt<4) [q rows prescaled]
//   proj tiles  [7168,9216)         (32 tiles: rt*4+kt, rt<8,  kt<4)
// wsB (float, at byte 147456): bias C-frags [h][nt][mt][lane]*4 = 16384 floats
#define WSB_BYTE_OFF 147456

__global__ __launch_bounds__(256) void prep_kernel(
    const float* __restrict__ conv_w, const float* __restrict__ trans_w,
    const float* __restrict__ qkv_w, const float* __restrict__ proj_w,
    const float* __restrict__ btab, const int* __restrict__ ridx,
    unsigned short* __restrict__ wsW, float* __restrict__ wsB)
{
    int id = blockIdx.x * 256 + threadIdx.x;
    if (id < 9216) {
        int lane = id & 63;
        int colr = lane & 15, quad = lane >> 4;
        const float* src;
        float scale = 1.0f;
        if (id < 512) {
            int tile = id >> 6; int rt = tile >> 1, kt = tile & 1;
            src = conv_w + (rt * 16 + colr) * 64 + kt * 32 + quad * 8;
        } else if (id < 1024) {
            int tile = (id - 512) >> 6; int rt = tile >> 1, kt = tile & 1;
            src = trans_w + (rt * 16 + colr) * 64 + kt * 32 + quad * 8;
        } else if (id < 7168) {
            int tile = (id - 1024) >> 6; int rt = tile >> 2, kt = tile & 3;
            int r = rt * 16 + colr;
            src = qkv_w + r * 128 + kt * 32 + quad * 8;
            if (r < 128) scale = 0.17677669529663689f;  // fold q * hd^-0.5 into weights
        } else {
            int tile = (id - 7168) >> 6; int rt = tile >> 2, kt = tile & 3;
            src = proj_w + (rt * 16 + colr) * 128 + kt * 32 + quad * 8;
        }
        bf16x8 r;
#pragma unroll
        for (int j = 0; j < 8; ++j) r[j] = (short)f2b(src[j] * scale);
        *reinterpret_cast<bf16x8*>(wsW + id * 8) = r;
    } else if (id < 13312) {
        int i = id - 9216;                        // 0..4095
        int h = i >> 10, nt = (i >> 8) & 3, mt = (i >> 6) & 3, lane = i & 63;
        int colr = lane & 15, quad = lane >> 4;
        f32x4 o;
#pragma unroll
        for (int g = 0; g < 4; ++g) {
            int n = nt * 16 + quad * 4 + g, m = mt * 16 + colr;
            o[g] = btab[ridx[n * 64 + m] * 4 + h];
        }
        *reinterpret_cast<f32x4*>(wsB + i * 4) = o;
    }
}

// ---- LDS: 3 regions of 8192 ushorts (48 KB total), lifetime-aliased ----
// A [0,8192):      XIN -> Q -> P[h0,h1] -> AO
// B [8192,16384):  X   -> K -> P[h2,h3] -> FU (fp32 4096)
// C [16384,24576): V
#define REG_A 0
#define REG_B 8192
#define REG_C 16384

// 128-wide rows (16 chunks of 8): xor-swizzle chunk so b128 frag reads stay <=2-way
__device__ __forceinline__ int idx128(int base, int t, int c) {
    int swz = ((c >> 3) ^ (t & 15) ^ ((t >> 4) & 3)) & 15;
    return base + t * 128 + (swz << 3) + (c & 7);
}
// 32-wide rows (4 chunks)
__device__ __forceinline__ int idxqk(int base, int h, int t, int d) {
    int swz = ((d >> 3) ^ (t & 3) ^ ((t >> 2) & 3)) & 3;
    return base + h * 2048 + t * 32 + (swz << 3) + (d & 7);
}
// V: v[h][d][64] in region C
__device__ __forceinline__ int idxv(int h, int d, int m) {
    int swz = ((m >> 3) ^ (d & 7)) & 7;
    return REG_C + h * 2048 + d * 64 + (swz << 3) + (m & 7);
}
// P: p[h][n][64] across A+B
__device__ __forceinline__ int idxp(int h, int n, int m) {
    int swz = ((m >> 3) ^ (n & 7)) & 7;
    return h * 4096 + n * 64 + (swz << 3) + (m & 7);
}
// FU: 4096 floats in region B, chunk-of-4 swizzle
__device__ __forceinline__ int idxfu(int c, int t) {
    int swz = ((t >> 2) ^ (c & 15)) & 15;
    return c * 64 + (swz << 2) + (t & 3);
}

__global__ __launch_bounds__(256, 3) void win_attn_kernel(
    const float* __restrict__ cfeat,
    const float* __restrict__ tfeat,
    const float* __restrict__ conv_b,
    const float* __restrict__ trans_b,
    const float* __restrict__ qkv_b,
    const float* __restrict__ proj_b,
    const unsigned short* __restrict__ wsW,
    const float* __restrict__ wsB,
    float* __restrict__ out)
{
    __shared__ unsigned short smem[24576];  // 48 KB
    float* fuf = reinterpret_cast<float*>(&smem[REG_B]);

    const int tid  = threadIdx.x;
    const int lane = tid & 63;
    const int wv   = tid >> 6;
    const int col  = lane & 15;
    const int quad = lane >> 4;

    // XCD swizzle: consecutive same-XCD dispatch slots get consecutive wx -> L2 line sharing
    int b   = blockIdx.x;
    int wid = ((b & 7) << 9) | (b >> 3);
    int wz = wid >> 8, wy = (wid >> 4) & 15, wx = wid & 15;
    const int vbase = wz * 16384 + wy * 256 + wx * 4;

    // ---- S1: global fp32 -> bf16 LDS XIN[t][cc] (A), ds_write_b128 per thread-iter ----
#pragma unroll
    for (int it = 0; it < 4; ++it) {
        int id = tid + (it << 8);          // 0..1023
        int cg = id >> 6;                  // 0..15 (8 conv groups, 8 trans groups)
        int t  = id & 63;
        int inp = cg >> 3;
        int c0  = (cg & 7) << 3;
        const float* src = (inp ? tfeat : cfeat) + (size_t)c0 * 262144 + vbase
                         + ((t >> 4) << 12) + (((t >> 2) & 3) << 6) + (t & 3);
        bf16x8 r;
#pragma unroll
        for (int j = 0; j < 8; ++j) r[j] = (short)f2b(src[(size_t)j * 262144]);
        *reinterpret_cast<bf16x8*>(&smem[idx128(REG_A, t, inp * 64 + c0)]) = r;
    }
    __syncthreads();                                   // 1

    // ---- S2: input projection -> X[t][o] (B) ----
    {
        int half = wv >> 1;
        const float* bvec = half ? trans_b : conv_b;
        bf16x8 afr[4][2];
#pragma unroll
        for (int tt = 0; tt < 4; ++tt)
#pragma unroll
            for (int kt = 0; kt < 2; ++kt)
                afr[tt][kt] = *reinterpret_cast<const bf16x8*>(
                    &smem[idx128(REG_A, tt * 16 + col, half * 64 + kt * 32 + quad * 8)]);
#pragma unroll
        for (int otl = 0; otl < 2; ++otl) {
            int rt  = (wv & 1) * 2 + otl;
            int row = rt * 16 + col;
            bf16x8 bfr[2];
#pragma unroll
            for (int kt = 0; kt < 2; ++kt)
                bfr[kt] = *reinterpret_cast<const bf16x8*>(
                    wsW + (half * 512 + (rt * 2 + kt) * 64 + lane) * 8);
            float bias = bvec[row];
            int oc = half * 64 + row;
#pragma unroll
            for (int tt = 0; tt < 4; ++tt) {
                f32x4 acc = {0.f, 0.f, 0.f, 0.f};
#pragma unroll
                for (int kt = 0; kt < 2; ++kt)
                    acc = __builtin_amdgcn_mfma_f32_16x16x32_bf16(afr[tt][kt], bfr[kt], acc, 0, 0, 0);
#pragma unroll
                for (int g = 0; g < 4; ++g)
                    smem[idx128(REG_B, tt * 16 + quad * 4 + g, oc)] = f2b(acc[g] + bias);
            }
        }
    }
    __syncthreads();                                   // 2

    // ---- S3: QKV; Q(A) K(B) V(C). Wave wv does row-tiles wv*6..wv*6+5 ----
    {
        bf16x8 afr[4][4];
#pragma unroll
        for (int tt = 0; tt < 4; ++tt)
#pragma unroll
            for (int kt = 0; kt < 4; ++kt)
                afr[tt][kt] = *reinterpret_cast<const bf16x8*>(
                    &smem[idx128(REG_B, tt * 16 + col, kt * 32 + quad * 8)]);
        __syncthreads();                               // 3 (X reads done; K may overwrite B)
        for (int rt = wv * 6; rt < wv * 6 + 6; ++rt) {
            int r = rt * 16 + col;
            bf16x8 bfr[4];
#pragma unroll
            for (int kt = 0; kt < 4; ++kt)
                bfr[kt] = *reinterpret_cast<const bf16x8*>(
                    wsW + (1024 + (rt * 4 + kt) * 64 + lane) * 8);
            float bias = qkv_b[r];
            int sel = r >> 7;           // 0:q 1:k 2:v (uniform per rt)
            int h   = (r >> 5) & 3;
            int d0  = r & 31;
            if (sel == 0) bias *= 0.17677669529663689f;
#pragma unroll
            for (int tt = 0; tt < 4; ++tt) {
                f32x4 acc = {0.f, 0.f, 0.f, 0.f};
#pragma unroll
                for (int kt = 0; kt < 4; ++kt)
                    acc = __builtin_amdgcn_mfma_f32_16x16x32_bf16(afr[tt][kt], bfr[kt], acc, 0, 0, 0);
#pragma unroll
                for (int g = 0; g < 4; ++g) {
                    int t = tt * 16 + quad * 4 + g;
                    float v = acc[g] + bias;
                    if (sel == 0)      smem[idxqk(REG_A, h, t, d0)] = f2b(v);
                    else if (sel == 1) smem[idxqk(REG_B, h, t, d0)] = f2b(v);
                    else               smem[idxv(h, d0, t)] = f2b(v);
                }
            }
        }
    }
    __syncthreads();                                   // 4

    // ---- S4a: scores = QK^T + bias (bias as MFMA C-init); exp; row sums; P unnorm ----
    float inv[4][4];
    {
        const int h = wv;
        bf16x8 qfr[4], kfr[4];
#pragma unroll
        for (int nt = 0; nt < 4; ++nt) {
            qfr[nt] = *reinterpret_cast<const bf16x8*>(&smem[idxqk(REG_A, h, nt * 16 + col, quad * 8)]);
            kfr[nt] = *reinterpret_cast<const bf16x8*>(&smem[idxqk(REG_B, h, nt * 16 + col, quad * 8)]);
        }
        __syncthreads();                               // 5 (Q/K reads done; P may overwrite A+B)
#pragma unroll
        for (int nt = 0; nt < 4; ++nt) {
            f32x4 s[4];
#pragma unroll
            for (int mt = 0; mt < 4; ++mt) {
                f32x4 binit = *reinterpret_cast<const f32x4*>(
                    wsB + ((h * 1024 + nt * 256 + mt * 64 + lane) << 2));
                s[mt] = __builtin_amdgcn_mfma_f32_16x16x32_bf16(qfr[nt], kfr[mt], binit, 0, 0, 0);
            }
#pragma unroll
            for (int g = 0; g < 4; ++g) {
                float e0 = __expf(fminf(s[0][g], 80.f));
                float e1 = __expf(fminf(s[1][g], 80.f));
                float e2 = __expf(fminf(s[2][g], 80.f));
                float e3 = __expf(fminf(s[3][g], 80.f));
                float sm = (e0 + e1) + (e2 + e3);
#pragma unroll
                for (int o = 1; o < 16; o <<= 1) sm += __shfl_xor(sm, o, 64);
                inv[nt][g] = 1.0f / sm;
                s[0][g] = e0; s[1][g] = e1; s[2][g] = e2; s[3][g] = e3;
            }
#pragma unroll
            for (int mt = 0; mt < 4; ++mt) {
                int m = mt * 16 + col;
#pragma unroll
                for (int g = 0; g < 4; ++g)
                    smem[idxp(h, nt * 16 + quad * 4 + g, m)] = f2b(s[mt][g]);
            }
        }
    }
    __syncthreads();                                   // 6

    // ---- S4b: O = (P V) * inv -> AO[t][c] (A) ----
    {
        const int h = wv;
        bf16x8 pfr[4][2], vfr[2][2];
#pragma unroll
        for (int dt = 0; dt < 2; ++dt)
#pragma unroll
            for (int kt = 0; kt < 2; ++kt)
                vfr[dt][kt] = *reinterpret_cast<const bf16x8*>(
                    &smem[idxv(h, dt * 16 + col, kt * 32 + quad * 8)]);
#pragma unroll
        for (int nt = 0; nt < 4; ++nt)
#pragma unroll
            for (int kt = 0; kt < 2; ++kt)
                pfr[nt][kt] = *reinterpret_cast<const bf16x8*>(
                    &smem[idxp(h, nt * 16 + col, kt * 32 + quad * 8)]);
        __syncthreads();                               // 7 (P reads done; AO may overwrite A)
#pragma unroll
        for (int nt = 0; nt < 4; ++nt)
#pragma unroll
            for (int dt = 0; dt < 2; ++dt) {
                f32x4 acc = {0.f, 0.f, 0.f, 0.f};
#pragma unroll
                for (int kt = 0; kt < 2; ++kt)
                    acc = __builtin_amdgcn_mfma_f32_16x16x32_bf16(pfr[nt][kt], vfr[dt][kt], acc, 0, 0, 0);
#pragma unroll
                for (int g = 0; g < 4; ++g)
                    smem[idx128(REG_A, nt * 16 + quad * 4 + g, h * 32 + dt * 16 + col)] =
                        f2b(acc[g] * inv[nt][g]);
            }
    }
    __syncthreads();                                   // 8

    // ---- S5: proj + fold halves + bias -> FU[c][t] fp32 (B), f32x4 writes ----
    {
        bf16x8 afr[4][4];
#pragma unroll
        for (int tt = 0; tt < 4; ++tt)
#pragma unroll
            for (int kt = 0; kt < 4; ++kt)
                afr[tt][kt] = *reinterpret_cast<const bf16x8*>(
                    &smem[idx128(REG_A, tt * 16 + col, kt * 32 + quad * 8)]);
        int o1 = wv * 16 + col;
        int o2 = 64 + o1;
        bf16x8 b1[4], b2[4];
#pragma unroll
        for (int kt = 0; kt < 4; ++kt) {
            b1[kt] = *reinterpret_cast<const bf16x8*>(wsW + (7168 + (wv * 4 + kt) * 64 + lane) * 8);
            b2[kt] = *reinterpret_cast<const bf16x8*>(wsW + (7168 + ((4 + wv) * 4 + kt) * 64 + lane) * 8);
        }
        float pb = proj_b[o1] + proj_b[o2];
#pragma unroll
        for (int tt = 0; tt < 4; ++tt) {
            f32x4 a1 = {0.f, 0.f, 0.f, 0.f}, a2 = {0.f, 0.f, 0.f, 0.f};
#pragma unroll
            for (int kt = 0; kt < 4; ++kt) {
                a1 = __builtin_amdgcn_mfma_f32_16x16x32_bf16(afr[tt][kt], b1[kt], a1, 0, 0, 0);
                a2 = __builtin_amdgcn_mfma_f32_16x16x32_bf16(afr[tt][kt], b2[kt], a2, 0, 0, 0);
            }
            f32x4 o;
#pragma unroll
            for (int g = 0; g < 4; ++g) o[g] = a1[g] + a2[g] + pb;
            *reinterpret_cast<f32x4*>(&fuf[idxfu(o1, tt * 16 + quad * 4)]) = o;
        }
    }
    __syncthreads();                                   // 9

    // ---- S6: out = FU + conv_feat residual, coalesced float4 ----
#pragma unroll
    for (int it = 0; it < 4; ++it) {
        int id = tid + (it << 8);       // 0..1023
        int c  = id >> 4;
        int z  = (id >> 2) & 3, y = id & 3;
        int t  = z * 16 + y * 4;
        f32x4 val = *reinterpret_cast<const f32x4*>(&fuf[idxfu(c, t)]);
        const float* rp = cfeat + (size_t)c * 262144 + vbase + z * 4096 + y * 64;
        f32x4 res = *reinterpret_cast<const f32x4*>(rp);
        f32x4 o;
#pragma unroll
        for (int g = 0; g < 4; ++g) o[g] = val[g] + res[g];
        *reinterpret_cast<f32x4*>(out + (size_t)c * 262144 + vbase + z * 4096 + y * 64) = o;
    }
}

extern "C" void kernel_launch(void* const* d_in, const int* in_sizes, int n_in,
                              void* d_out, int out_size, void* d_ws, size_t ws_size,
                              hipStream_t stream) {
    (void)in_sizes; (void)n_in; (void)out_size; (void)ws_size;
    unsigned short* wsW = (unsigned short*)d_ws;
    float* wsB = (float*)((char*)d_ws + WSB_BYTE_OFF);

    prep_kernel<<<dim3(52), dim3(256), 0, stream>>>(
        (const float*)d_in[2],  // conv_w
        (const float*)d_in[4],  // trans_w
        (const float*)d_in[6],  // qkv_w
        (const float*)d_in[8],  // proj_w
        (const float*)d_in[10], // rel_bias_table
        (const int*)d_in[11],   // rel_index
        wsW, wsB);

    win_attn_kernel<<<dim3(4096), dim3(256), 0, stream>>>(
        (const float*)d_in[0],  // conv_feat
        (const float*)d_in[1],  // transformer_feat
        (const float*)d_in[3],  // conv_b
        (const float*)d_in[5],  // trans_b
        (const float*)d_in[7],  // qkv_b
        (const float*)d_in[9],  // proj_b
        wsW, wsB,
        (float*)d_out);
}